// Round 15
// baseline (335.729 us; speedup 1.0000x reference)
//
#include <hip/hip_runtime.h>
#include <hip/hip_fp16.h>
#include <math.h>

#define GHH 224
#define GWW 224
#define HW (GHH*GWW)     // 50176
#define BATCH 8
#define RAD 3
#define DIAM 7
#define QC 32
// 16x32 tile, 256 threads, 1x2 px/thread
#define TH 16
#define TW 32
#define QTH (TH + 2*RAD)    // 22
#define QTW (TW + 2*RAD)    // 38
#define QR 40               // LDS row stride (float4 slots)
#define QP 882              // chunk-plane stride (float4)
#define QPIX (QTH*QTW)      // 836
// smem: sq 4*882*16 = 56448 | sh 880*16 = 14080  => 70528 B -> 2 blocks/CU
#define SQ_B (4*QP*16)

typedef _Float16 h2 __attribute__((ext_vector_type(2)));
typedef _Float16 v8h __attribute__((ext_vector_type(8)));
typedef float v4f __attribute__((ext_vector_type(4)));

#if defined(__has_builtin)
#if __has_builtin(__builtin_amdgcn_fdot2)
#define HAS_FDOT2 1
#endif
#endif

__device__ __forceinline__ h2 as_h2(float f) { union { float f; h2 h; } u; u.f = f; return u.h; }

__device__ __forceinline__ float dot2acc(float a, float b, float acc) {
#ifdef HAS_FDOT2
    return __builtin_amdgcn_fdot2(as_h2(a), as_h2(b), acc, false);
#else
    union { float f; __half2 h; } ua, ub; ua.f = a; ub.f = b;
    float2 fa = __half22float2(ua.h), fb = __half22float2(ub.h);
    return acc + fa.x * fb.x + fa.y * fb.y;
#endif
}

__device__ __forceinline__ float dot16(const float4& a, const float4& b, float acc) {
    acc = dot2acc(a.x, b.x, acc);
    acc = dot2acc(a.y, b.y, acc);
    acc = dot2acc(a.z, b.z, acc);
    acc = dot2acc(a.w, b.w, acc);
    return acc;
}

__device__ __forceinline__ int refl(int i) {
    if (i < 0) i = -i;
    if (i >= GHH) i = 2 * GHH - 2 - i;
    return i;
}

__device__ __forceinline__ float gelu_fast(float v) {
    float u = 0.7978845608f * v * (1.f + 0.044715f * v * v);
    float e = __expf(2.f * u);
    float th = 1.f - 2.f / (e + 1.f);
    return 0.5f * v * (1.f + th);
}

// ---------------- linear + w2 B-frag prep + w1 f16 pack + guid4 pack ----------------
__global__ void linear_prep_kernel(const float* __restrict__ x,
                                   const float* __restrict__ W,
                                   const float* __restrict__ bias,
                                   float* __restrict__ f0,
                                   const float* __restrict__ w2s,
                                   __half* __restrict__ wsB,
                                   const float* __restrict__ w1s,
                                   const float* __restrict__ b1s,
                                   __half* __restrict__ wsW1,
                                   const float* __restrict__ guid,
                                   float4* __restrict__ guid4) {
    int blk = blockIdx.x;
    if (blk >= 1946) {   // guid4 pack: 1568 blocks
        int i = (blk - 1946) * 256 + threadIdx.x;
        int b = i / HW, pix = i % HW;
        guid4[i] = make_float4(guid[(b * 3) * HW + pix],
                               guid[(b * 3 + 1) * HW + pix],
                               guid[(b * 3 + 2) * HW + pix], 0.f);
        return;
    }
    if (blk == 1945) {   // pack w1/b1 (4 stages x 32 ch) into f16 quads (w0,w1,w2,b)
        int tid = threadIdx.x;
        if (tid < 128) {
            int s = tid >> 5, c = tid & 31;
            wsW1[tid * 4 + 0] = __float2half(w1s[s * 96 + c * 3 + 0]);
            wsW1[tid * 4 + 1] = __float2half(w1s[s * 96 + c * 3 + 1]);
            wsW1[tid * 4 + 2] = __float2half(w1s[s * 96 + c * 3 + 2]);
            wsW1[tid * 4 + 3] = __float2half(b1s[s * 32 + c]);
        }
        return;
    }
    if (blk == 1944) {   // pack w2 (4 stages) into f16 MFMA B-fragments
        int tid = threadIdx.x;
        int s = tid >> 6, l = tid & 63;
        int n0 = l & 15, kq = l >> 4;
        const float* w2 = w2s + s * 1024;
        __half* dst = wsB + (size_t)tid * 16;
        #pragma unroll
        for (int j = 0; j < 8; j++) {
            dst[j]     = __float2half(w2[n0 * QC + kq * 8 + j]);
            dst[8 + j] = __float2half(w2[(n0 + 16) * QC + kq * 8 + j]);
        }
        return;
    }
    int gwave = (blk * blockDim.x + threadIdx.x) >> 6;
    int lane = threadIdx.x & 63;
    if (gwave >= BATCH * 972) return;
    int b = gwave / 972, j = gwave % 972;
    const float* xr = x + b * 1000;
    const float* wr = W + j * 1000;
    float s = 0.f;
    for (int k = lane; k < 1000; k += 64)
        s += xr[k] * wr[k];
    #pragma unroll
    for (int off = 32; off; off >>= 1) s += __shfl_down(s, off, 64);
    if (lane == 0) f0[gwave] = s + bias[j];
}

// ---------------- bicubic 18 -> 224, float4-interleaved output ----------------
__device__ __forceinline__ float cubicw(float d) {
    d = fabsf(d);
    if (d <= 1.f) return ((1.25f * d - 2.25f) * d) * d + 1.f;
    if (d < 2.f)  return ((-0.75f * d + 3.75f) * d - 6.f) * d + 3.f;
    return 0.f;
}

__global__ void bicubic_kernel(const float* __restrict__ f0, float4* __restrict__ hr4) {
    int idx = blockIdx.x * blockDim.x + threadIdx.x;
    if (idx >= BATCH * HW) return;
    int pix = idx % HW;
    int b = idx / HW;
    int w = pix % GWW, h = pix / GWW;
    float xx = (w + 0.5f) * (18.f / 224.f) - 0.5f;
    float yy = (h + 0.5f) * (18.f / 224.f) - 0.5f;
    float fx0 = floorf(xx), fy0 = floorf(yy);
    int x0 = (int)fx0, y0 = (int)fy0;
    float tx = xx - fx0, ty = yy - fy0;
    float wx[4], wy[4];
    int ix[4], iy[4];
    #pragma unroll
    for (int k = 0; k < 4; k++) {
        wx[k] = cubicw(tx - (float)(k - 1));
        wy[k] = cubicw(ty - (float)(k - 1));
        int a = x0 + (k - 1); ix[k] = min(max(a, 0), 17);
        a = y0 + (k - 1);     iy[k] = min(max(a, 0), 17);
    }
    float acc[3];
    #pragma unroll
    for (int c = 0; c < 3; c++) {
        const float* src = f0 + (b * 3 + c) * 324;
        float a = 0.f;
        #pragma unroll
        for (int ky = 0; ky < 4; ky++) {
            float rowv = 0.f;
            #pragma unroll
            for (int kx = 0; kx < 4; kx++) rowv += wx[kx] * src[iy[ky] * 18 + ix[kx]];
            a += wy[ky] * rowv;
        }
        acc[c] = a;
    }
    hr4[idx] = make_float4(acc[0], acc[1], acc[2], 0.f);
}

// ---------------- fused JBU: 16x32 tile, 1x2 px/thread, streaming max-free softmax ----------------
// LDS col swizzle: halo col c -> slot (c>>1) + (c&1)*19  => tap reads lane-stride 16B (R9-proven)
__global__ __launch_bounds__(256, 2) void jbu_kernel(
    const float4* __restrict__ guid4,
    const __half* __restrict__ wsW1,
    const __half* __restrict__ wsB, const float* __restrict__ b2,
    const float4* __restrict__ hr4,
    float4* __restrict__ out4,
    float* __restrict__ outP,
    const float* __restrict__ temps,
    const float* __restrict__ sigmas,
    int stage)
{
    __shared__ __align__(16) char smem[SQ_B + QTH * QR * 16];  // 70528 B
    float4* sq = (float4*)smem;                 // q tile f16, 4 chunk planes, swizzled slots
    float4* sh = (float4*)(smem + SQ_B);        // hr tile, swizzled slots

    const int tx = threadIdx.x, ty = threadIdx.y;
    const int tid = ty * 16 + tx;
    const int b = blockIdx.z;
    const int h0 = blockIdx.y * TH, w0 = blockIdx.x * TW;

    const bool interior = (h0 >= RAD) && (h0 + TH + RAD <= GHH) &&
                          (w0 >= RAD) && (w0 + TW + RAD <= GWW);

    // ---- stage hr tile into swizzled slots ----
    if (interior) {
        const float4* hb = hr4 + (size_t)b * HW + (size_t)(h0 - RAD) * GWW + (w0 - RAD);
        for (int i = tid; i < QPIX; i += 256) {
            int r = i / QTW, c = i - r * QTW;
            sh[r * QR + (c >> 1) + (c & 1) * 19] = hb[(size_t)r * GWW + c];
        }
    } else {
        for (int i = tid; i < QPIX; i += 256) {
            int r = i / QTW, c = i - r * QTW;
            int gh = refl(h0 - RAD + r);
            int gw = refl(w0 - RAD + c);
            sh[r * QR + (c >> 1) + (c & 1) * 19] = hr4[(size_t)b * HW + (size_t)gh * GWW + gw];
        }
    }

    // ---- phase 0: q tile, scratch-free per-lane A-frag MFMA (R14-proven), 836 halo px ----
    const int w = tid >> 6, l = tid & 63;
    const int n0 = l & 15, kq = l >> 4;
    const v8h* Bp = (const v8h*)(wsB + ((size_t)stage * 64 + l) * 16);
    const v8h B0 = Bp[0], B1 = Bp[1];
    const float bias0 = b2[n0], bias1 = b2[n0 + 16];
    union { _Float16 h[32]; float4 f4[4]; } W1;
    {
        const float4* wp = (const float4*)(wsW1 + stage * 128 + kq * 32);
        W1.f4[0] = wp[0]; W1.f4[1] = wp[1]; W1.f4[2] = wp[2]; W1.f4[3] = wp[3];
    }

    #pragma unroll 1
    for (int r2 = 0; r2 < 4; r2++) {
        #pragma unroll
        for (int tt = 0; tt < 4; tt++) {
            int base = r2 * 256 + w * 64 + tt * 16;
            if (base >= QPIX) break;
            int p = base + n0;
            int pc = min(p, QPIX - 1);
            int rr = pc / QTW, cc = pc - rr * QTW;
            int gh = refl(h0 - RAD + rr), gw = refl(w0 - RAD + cc);
            float4 g = guid4[(size_t)b * HW + (size_t)gh * GWW + gw];
            union { _Float16 h[8]; v8h v; } A;
            #pragma unroll
            for (int j = 0; j < 8; j++) {
                float vv = fmaf((float)W1.h[j * 4], g.x,
                           fmaf((float)W1.h[j * 4 + 1], g.y,
                           fmaf((float)W1.h[j * 4 + 2], g.z, (float)W1.h[j * 4 + 3])));
                A.h[j] = (_Float16)gelu_fast(vv);
            }
            v4f D0 = {0.f, 0.f, 0.f, 0.f}, D1 = {0.f, 0.f, 0.f, 0.f};
            D0 = __builtin_amdgcn_mfma_f32_16x16x32_f16(A.v, B0, D0, 0, 0, 0);
            D1 = __builtin_amdgcn_mfma_f32_16x16x32_f16(A.v, B1, D1, 0, 0, 0);
            #pragma unroll
            for (int r = 0; r < 4; r++) {
                int gpx = base + 4 * kq + r;   // C/D row = pixel (verified mapping)
                if (gpx < QPIX) {
                    int rr2 = gpx / QTW, cc2 = gpx - rr2 * QTW;
                    int slot = rr2 * QR + (cc2 >> 1) + (cc2 & 1) * 19;
                    *(_Float16*)(smem + ((n0 >> 3) * QP + slot) * 16 + (n0 & 7) * 2)
                        = (_Float16)(D0[r] + bias0);
                    *(_Float16*)(smem + (((n0 >> 3) + 2) * QP + slot) * 16 + (n0 & 7) * 2)
                        = (_Float16)(D1[r] + bias1);
                }
            }
        }
    }
    __syncthreads();

    // ---- centers: px0 halo col 2tx+3 -> slot tx+20 ; px1 halo col 2tx+4 -> slot tx+2 ----
    float4 A0c[4], A1c[4];
    {
        int rbc = (ty + RAD) * QR;
        #pragma unroll
        for (int c = 0; c < 4; c++) {
            A0c[c] = sq[c * QP + rbc + tx + 20];
            A1c[c] = sq[c * QP + rbc + tx + 2];
        }
    }

    // ---- streaming pass: scores + exp + spatial + conv, no score storage ----
    float t = __expf(temps[stage]);
    t = fminf(fmaxf(t, 1e-4f), 1e4f);
    float sig = sigmas[stage];
    float inv2s2 = 1.f / (2.f * sig * sig);
    float sd[DIAM];
    #pragma unroll
    for (int i = 0; i < DIAM; i++) {
        float d = (float)(i - 3) * (1.f / 3.f);
        sd[i] = __expf(-d * d * inv2s2);
    }

    float es0 = 0.f, ws0 = 0.f, n00 = 0.f, n01 = 0.f, n02 = 0.f;
    float es1 = 0.f, ws1 = 0.f, n10 = 0.f, n11 = 0.f, n12 = 0.f;
    #pragma unroll
    for (int di = 0; di < DIAM; di++) {
        const int rb = (ty + di) * QR + tx;
        const float sy = sd[di];
        #pragma unroll
        for (int dj = 0; dj < 8; dj++) {
            const int SOFF = (dj >> 1) + (dj & 1) * 19;   // 0,19,1,20,2,21,3,22
            const int ni = rb + SOFF;
            float4 v0 = sq[ni], v1 = sq[QP + ni], v2 = sq[2 * QP + ni], v3 = sq[3 * QP + ni];
            float4 hv = sh[ni];
            if (dj < 7) {
                float s = dot16(A0c[0], v0, 0.f);
                s = dot16(A0c[1], v1, s);
                s = dot16(A0c[2], v2, s);
                s = dot16(A0c[3], v3, s);
                float e = __expf(t * s);           // max-free: |t*s| << 1 for this model
                float wgt = e * sy * sd[dj];
                es0 += e; ws0 += wgt;
                n00 += wgt * hv.x; n01 += wgt * hv.y; n02 += wgt * hv.z;
            }
            if (dj > 0) {
                float s = dot16(A1c[0], v0, 0.f);
                s = dot16(A1c[1], v1, s);
                s = dot16(A1c[2], v2, s);
                s = dot16(A1c[3], v3, s);
                float e = __expf(t * s);
                float wgt = e * sy * sd[dj - 1];
                es1 += e; ws1 += wgt;
                n10 += wgt * hv.x; n11 += wgt * hv.y; n12 += wgt * hv.z;
            }
        }
    }
    float r0 = 1.f / fmaxf(ws0, 1e-7f * es0);
    float r1 = 1.f / fmaxf(ws1, 1e-7f * es1);

    if (stage < 3) {
        size_t obase = (size_t)b * HW + (size_t)(h0 + ty) * GWW + (w0 + 2 * tx);
        out4[obase]     = make_float4(n00 * r0, n01 * r0, n02 * r0, 0.f);
        out4[obase + 1] = make_float4(n10 * r1, n11 * r1, n12 * r1, 0.f);
    } else {
        size_t obase = (size_t)b * 3 * HW + (size_t)(h0 + ty) * GWW + (w0 + 2 * tx);
        *(float2*)&outP[obase]          = make_float2(n00 * r0, n10 * r1);
        *(float2*)&outP[obase + HW]     = make_float2(n01 * r0, n11 * r1);
        *(float2*)&outP[obase + 2 * HW] = make_float2(n02 * r0, n12 * r1);
    }
}

extern "C" void kernel_launch(void* const* d_in, const int* in_sizes, int n_in,
                              void* d_out, int out_size, void* d_ws, size_t ws_size,
                              hipStream_t stream) {
    const float* x      = (const float*)d_in[0];
    const float* guid   = (const float*)d_in[1];
    const float* lw     = (const float*)d_in[2];
    const float* lb     = (const float*)d_in[3];
    const float* w1s    = (const float*)d_in[4];
    const float* b1s    = (const float*)d_in[5];
    const float* w2s    = (const float*)d_in[6];
    const float* b2s    = (const float*)d_in[7];
    const float* temps  = (const float*)d_in[8];
    const float* sigmas = (const float*)d_in[9];

    char* ws = (char*)d_ws;
    const size_t P4_BYTES = (size_t)BATCH * HW * sizeof(float4);      // 6,422,528
    float4* guid4 = (float4*)ws;
    float4* hr4A  = (float4*)(ws + P4_BYTES);
    float4* hr4B  = (float4*)(ws + 2 * P4_BYTES);
    float*  f0    = (float*)(ws + 3 * P4_BYTES);                      // 31,104 B
    __half* wsB   = (__half*)(ws + 3 * P4_BYTES + 31104);             //  8,192 B
    __half* wsW1  = (__half*)(ws + 3 * P4_BYTES + 31104 + 8192);      //  1,024 B

    linear_prep_kernel<<<1946 + 1568, 256, 0, stream>>>(
        x, lw, lb, f0, w2s, wsB, w1s, b1s, wsW1, guid, guid4);
    bicubic_kernel<<<(BATCH * HW + 255) / 256, 256, 0, stream>>>(f0, hr4A);

    dim3 jgrid(GWW / TW, GHH / TH, BATCH), jblock(16, 16);
    const float4* hins[4]  = { hr4A, hr4B, hr4A, hr4B };
    float4*       fouts[4] = { hr4B, hr4A, hr4B, nullptr };
    for (int s = 0; s < 4; s++) {
        jbu_kernel<<<jgrid, jblock, 0, stream>>>(
            guid4, wsW1, wsB, b2s + s * 32,
            hins[s], fouts[s], (s == 3) ? (float*)d_out : nullptr,
            temps, sigmas, s);
    }
}

// Round 16
// 279.541 us; speedup vs baseline: 1.2010x; 1.2010x over previous
//
#include <hip/hip_runtime.h>
#include <hip/hip_fp16.h>
#include <math.h>

#define GHH 224
#define GWW 224
#define HW (GHH*GWW)     // 50176
#define BATCH 8
#define RAD 3
#define DIAM 7
#define QC 32
#define TILE 16
#define TP (TILE + 2*RAD)   // 22
#define TPIX (TP*TP)        // 484
#define CS 485              // chunk-plane stride in float4 (proven layout)
// smem: sq 4*485*16 = 31040 | sh 484*16 = 7744  => 38784 B -> 4 blocks/CU
#define SQ_B 31040

typedef _Float16 h2 __attribute__((ext_vector_type(2)));
typedef _Float16 v8h __attribute__((ext_vector_type(8)));
typedef float v4f __attribute__((ext_vector_type(4)));

#if defined(__has_builtin)
#if __has_builtin(__builtin_amdgcn_fdot2)
#define HAS_FDOT2 1
#endif
#endif

__device__ __forceinline__ h2 as_h2(float f) { union { float f; h2 h; } u; u.f = f; return u.h; }

__device__ __forceinline__ float dot2acc(float a, float b, float acc) {
#ifdef HAS_FDOT2
    return __builtin_amdgcn_fdot2(as_h2(a), as_h2(b), acc, false);
#else
    union { float f; __half2 h; } ua, ub; ua.f = a; ub.f = b;
    float2 fa = __half22float2(ua.h), fb = __half22float2(ub.h);
    return acc + fa.x * fb.x + fa.y * fb.y;
#endif
}

__device__ __forceinline__ float dot16(const float4& a, const float4& b, float acc) {
    acc = dot2acc(a.x, b.x, acc);
    acc = dot2acc(a.y, b.y, acc);
    acc = dot2acc(a.z, b.z, acc);
    acc = dot2acc(a.w, b.w, acc);
    return acc;
}

__device__ __forceinline__ int refl(int i) {
    if (i < 0) i = -i;
    if (i >= GHH) i = 2 * GHH - 2 - i;
    return i;
}

__device__ __forceinline__ float gelu_fast(float v) {
    float u = 0.7978845608f * v * (1.f + 0.044715f * v * v);
    float e = __expf(2.f * u);
    float th = 1.f - 2.f / (e + 1.f);
    return 0.5f * v * (1.f + th);
}

// ---------------- linear + w2 B-frag prep + w1 f16 pack + guid4 pack ----------------
__global__ void linear_prep_kernel(const float* __restrict__ x,
                                   const float* __restrict__ W,
                                   const float* __restrict__ bias,
                                   float* __restrict__ f0,
                                   const float* __restrict__ w2s,
                                   __half* __restrict__ wsB,
                                   const float* __restrict__ w1s,
                                   const float* __restrict__ b1s,
                                   __half* __restrict__ wsW1,
                                   const float* __restrict__ guid,
                                   float4* __restrict__ guid4) {
    int blk = blockIdx.x;
    if (blk >= 1946) {   // guid4 pack: 1568 blocks
        int i = (blk - 1946) * 256 + threadIdx.x;
        int b = i / HW, pix = i % HW;
        guid4[i] = make_float4(guid[(b * 3) * HW + pix],
                               guid[(b * 3 + 1) * HW + pix],
                               guid[(b * 3 + 2) * HW + pix], 0.f);
        return;
    }
    if (blk == 1945) {   // pack w1/b1 (4 stages x 32 ch) into f16 quads (w0,w1,w2,b)
        int tid = threadIdx.x;
        if (tid < 128) {
            int s = tid >> 5, c = tid & 31;
            wsW1[tid * 4 + 0] = __float2half(w1s[s * 96 + c * 3 + 0]);
            wsW1[tid * 4 + 1] = __float2half(w1s[s * 96 + c * 3 + 1]);
            wsW1[tid * 4 + 2] = __float2half(w1s[s * 96 + c * 3 + 2]);
            wsW1[tid * 4 + 3] = __float2half(b1s[s * 32 + c]);
        }
        return;
    }
    if (blk == 1944) {   // pack w2 (4 stages) into f16 MFMA fragments
        int tid = threadIdx.x;
        int s = tid >> 6, l = tid & 63;
        int n0 = l & 15, kq = l >> 4;
        const float* w2 = w2s + s * 1024;
        __half* dst = wsB + (size_t)tid * 16;
        #pragma unroll
        for (int j = 0; j < 8; j++) {
            dst[j]     = __float2half(w2[n0 * QC + kq * 8 + j]);
            dst[8 + j] = __float2half(w2[(n0 + 16) * QC + kq * 8 + j]);
        }
        return;
    }
    int gwave = (blk * blockDim.x + threadIdx.x) >> 6;
    int lane = threadIdx.x & 63;
    if (gwave >= BATCH * 972) return;
    int b = gwave / 972, j = gwave % 972;
    const float* xr = x + b * 1000;
    const float* wr = W + j * 1000;
    float s = 0.f;
    for (int k = lane; k < 1000; k += 64)
        s += xr[k] * wr[k];
    #pragma unroll
    for (int off = 32; off; off >>= 1) s += __shfl_down(s, off, 64);
    if (lane == 0) f0[gwave] = s + bias[j];
}

// ---------------- bicubic 18 -> 224, float4-interleaved output ----------------
__device__ __forceinline__ float cubicw(float d) {
    d = fabsf(d);
    if (d <= 1.f) return ((1.25f * d - 2.25f) * d) * d + 1.f;
    if (d < 2.f)  return ((-0.75f * d + 3.75f) * d - 6.f) * d + 3.f;
    return 0.f;
}

__global__ void bicubic_kernel(const float* __restrict__ f0, float4* __restrict__ hr4) {
    int idx = blockIdx.x * blockDim.x + threadIdx.x;
    if (idx >= BATCH * HW) return;
    int pix = idx % HW;
    int b = idx / HW;
    int w = pix % GWW, h = pix / GWW;
    float xx = (w + 0.5f) * (18.f / 224.f) - 0.5f;
    float yy = (h + 0.5f) * (18.f / 224.f) - 0.5f;
    float fx0 = floorf(xx), fy0 = floorf(yy);
    int x0 = (int)fx0, y0 = (int)fy0;
    float tx = xx - fx0, ty = yy - fy0;
    float wx[4], wy[4];
    int ix[4], iy[4];
    #pragma unroll
    for (int k = 0; k < 4; k++) {
        wx[k] = cubicw(tx - (float)(k - 1));
        wy[k] = cubicw(ty - (float)(k - 1));
        int a = x0 + (k - 1); ix[k] = min(max(a, 0), 17);
        a = y0 + (k - 1);     iy[k] = min(max(a, 0), 17);
    }
    float acc[3];
    #pragma unroll
    for (int c = 0; c < 3; c++) {
        const float* src = f0 + (b * 3 + c) * 324;
        float a = 0.f;
        #pragma unroll
        for (int ky = 0; ky < 4; ky++) {
            float rowv = 0.f;
            #pragma unroll
            for (int kx = 0; kx < 4; kx++) rowv += wx[kx] * src[iy[ky] * 18 + ix[kx]];
            a += wy[ky] * rowv;
        }
        acc[c] = a;
    }
    hr4[idx] = make_float4(acc[0], acc[1], acc[2], 0.f);
}

// ---------------- fused JBU: swapped-operand q-compute (b64 D-writes) + streaming softmax ----------------
__global__ __launch_bounds__(256, 4) void jbu_kernel(
    const float4* __restrict__ guid4,
    const __half* __restrict__ wsW1,
    const __half* __restrict__ wsB, const float* __restrict__ b2,
    const float4* __restrict__ hr4,
    float4* __restrict__ out4,
    float* __restrict__ outP,
    const float* __restrict__ temps,
    const float* __restrict__ sigmas,
    int stage)
{
    __shared__ __align__(16) char smem[SQ_B + TPIX * 16];  // 38784 B
    float4* sq = (float4*)smem;                 // q tile f16 chunk-planar [4][CS]
    float4* sh = (float4*)(smem + SQ_B);        // hr tile (3ch + pad)

    const int tx = threadIdx.x, ty = threadIdx.y;
    const int tid = ty * TILE + tx;
    const int b = blockIdx.z;
    const int h0 = blockIdx.y * TILE, w0 = blockIdx.x * TILE;

    // ---- stage hr tile ----
    const bool interior = (h0 >= RAD) && (h0 + TILE + RAD <= GHH) &&
                          (w0 >= RAD) && (w0 + TILE + RAD <= GWW);
    if (interior) {
        const float4* hb = hr4 + (size_t)b * HW + (size_t)(h0 - RAD) * GWW + (w0 - RAD);
        for (int i = tid; i < TPIX; i += 256) {
            int r = i / TP, cx = i % TP;
            sh[i] = hb[(size_t)r * GWW + cx];
        }
    } else {
        for (int i = tid; i < TPIX; i += 256) {
            int r = i / TP, cx = i % TP;
            int gh = refl(h0 - RAD + r);
            int gw = refl(w0 - RAD + cx);
            sh[i] = hr4[(size_t)b * HW + (size_t)gh * GWW + gw];
        }
    }

    // ---- phase 0: q tile. Swapped operands: A = w2 frag, B = per-lane h1 frag.
    //      D[m=channel][n=pixel]: lane (kq,n0) gets channels 4kq..4kq+3 of its OWN
    //      pixel base+n0 -> one aligned 8B chunk-planar write (ds_write_b64). ----
    const int w = tid >> 6, l = tid & 63;
    const int n0 = l & 15, kq = l >> 4;
    const v8h* Bp = (const v8h*)(wsB + ((size_t)stage * 64 + l) * 16);
    const v8h W2a = Bp[0], W2b = Bp[1];       // w2 fragments (serve as A now)
    const float4 b2a = *(const float4*)(b2 + 4 * kq);        // ch 4kq..4kq+3
    const float4 b2b = *(const float4*)(b2 + 16 + 4 * kq);   // ch 16+4kq..
    union { _Float16 h[32]; float4 f4[4]; } W1;
    {
        const float4* wp = (const float4*)(wsW1 + stage * 128 + kq * 32);
        W1.f4[0] = wp[0]; W1.f4[1] = wp[1]; W1.f4[2] = wp[2]; W1.f4[3] = wp[3];
    }
    const int plane0 = kq >> 1;               // D0 -> plane 0/1, D1 -> plane 2/3
    const int boff   = (kq & 1) * 8;          // low/high 8B of the 16B px record

    #pragma unroll 1
    for (int r2 = 0; r2 < 2; r2++) {
        #pragma unroll
        for (int tt = 0; tt < 4; tt++) {
            int base = r2 * 256 + w * 64 + tt * 16;
            int p = base + n0;                // lane's own pixel
            int pc = min(p, TPIX - 1);
            int rr = pc / TP, cc = pc - rr * TP;
            int gh = refl(h0 - RAD + rr), gw = refl(w0 - RAD + cc);
            float4 g = guid4[(size_t)b * HW + (size_t)gh * GWW + gw];
            union { _Float16 h[8]; v8h v; } A;
            #pragma unroll
            for (int j = 0; j < 8; j++) {
                float vv = fmaf((float)W1.h[j * 4], g.x,
                           fmaf((float)W1.h[j * 4 + 1], g.y,
                           fmaf((float)W1.h[j * 4 + 2], g.z, (float)W1.h[j * 4 + 3])));
                A.h[j] = (_Float16)gelu_fast(vv);
            }
            v4f D0 = {0.f, 0.f, 0.f, 0.f}, D1 = {0.f, 0.f, 0.f, 0.f};
            D0 = __builtin_amdgcn_mfma_f32_16x16x32_f16(W2a, A.v, D0, 0, 0, 0);
            D1 = __builtin_amdgcn_mfma_f32_16x16x32_f16(W2b, A.v, D1, 0, 0, 0);
            if (p < TPIX) {
                union { _Float16 h[4]; uint2 u; } q0, q1;
                q0.h[0] = (_Float16)(D0[0] + b2a.x);
                q0.h[1] = (_Float16)(D0[1] + b2a.y);
                q0.h[2] = (_Float16)(D0[2] + b2a.z);
                q0.h[3] = (_Float16)(D0[3] + b2a.w);
                q1.h[0] = (_Float16)(D1[0] + b2b.x);
                q1.h[1] = (_Float16)(D1[1] + b2b.y);
                q1.h[2] = (_Float16)(D1[2] + b2b.z);
                q1.h[3] = (_Float16)(D1[3] + b2b.w);
                *(uint2*)(smem + (plane0 * CS + p) * 16 + boff)       = q0.u;
                *(uint2*)(smem + ((2 + plane0) * CS + p) * 16 + boff) = q1.u;
            }
        }
    }
    __syncthreads();   // sq + sh ready

    // ---- streaming pass: scores + max-free exp + spatial + conv (R15-validated numerics) ----
    int ci = (ty + RAD) * TP + tx + RAD;
    float4 c0 = sq[ci], c1 = sq[CS + ci], c2 = sq[2 * CS + ci], c3 = sq[3 * CS + ci];

    float t = __expf(temps[stage]);
    t = fminf(fmaxf(t, 1e-4f), 1e4f);
    float sig = sigmas[stage];
    float inv2s2 = 1.f / (2.f * sig * sig);
    float sd[DIAM];
    #pragma unroll
    for (int i = 0; i < DIAM; i++) {
        float d = (float)(i - 3) * (1.f / 3.f);
        sd[i] = __expf(-d * d * inv2s2);
    }

    float es = 0.f, wsum = 0.f, o0 = 0.f, o1 = 0.f, o2 = 0.f;
    #pragma unroll
    for (int di = 0; di < DIAM; di++) {
        int rb = (ty + di) * TP + tx;
        float sy = sd[di];
        #pragma unroll
        for (int dj = 0; dj < DIAM; dj++) {
            int ni = rb + dj;
            float s = dot16(c0, sq[ni], 0.f);
            s = dot16(c1, sq[CS + ni], s);
            s = dot16(c2, sq[2 * CS + ni], s);
            s = dot16(c3, sq[3 * CS + ni], s);
            float4 hv = sh[ni];
            float e = __expf(t * s);           // max-free: |t*s| << 1 for this model
            float wgt = e * sy * sd[dj];
            es += e; wsum += wgt;
            o0 += wgt * hv.x; o1 += wgt * hv.y; o2 += wgt * hv.z;
        }
    }
    float rk = 1.f / fmaxf(wsum, 1e-7f * es);

    if (stage < 3) {
        out4[(size_t)b * HW + (size_t)(h0 + ty) * GWW + (w0 + tx)] =
            make_float4(o0 * rk, o1 * rk, o2 * rk, 0.f);
    } else {
        size_t obase = (size_t)b * 3 * HW + (size_t)(h0 + ty) * GWW + (w0 + tx);
        outP[obase]          = o0 * rk;
        outP[obase + HW]     = o1 * rk;
        outP[obase + 2 * HW] = o2 * rk;
    }
}

extern "C" void kernel_launch(void* const* d_in, const int* in_sizes, int n_in,
                              void* d_out, int out_size, void* d_ws, size_t ws_size,
                              hipStream_t stream) {
    const float* x      = (const float*)d_in[0];
    const float* guid   = (const float*)d_in[1];
    const float* lw     = (const float*)d_in[2];
    const float* lb     = (const float*)d_in[3];
    const float* w1s    = (const float*)d_in[4];
    const float* b1s    = (const float*)d_in[5];
    const float* w2s    = (const float*)d_in[6];
    const float* b2s    = (const float*)d_in[7];
    const float* temps  = (const float*)d_in[8];
    const float* sigmas = (const float*)d_in[9];

    char* ws = (char*)d_ws;
    const size_t P4_BYTES = (size_t)BATCH * HW * sizeof(float4);      // 6,422,528
    float4* guid4 = (float4*)ws;
    float4* hr4A  = (float4*)(ws + P4_BYTES);
    float4* hr4B  = (float4*)(ws + 2 * P4_BYTES);
    float*  f0    = (float*)(ws + 3 * P4_BYTES);                      // 31,104 B
    __half* wsB   = (__half*)(ws + 3 * P4_BYTES + 31104);             //  8,192 B
    __half* wsW1  = (__half*)(ws + 3 * P4_BYTES + 31104 + 8192);      //  1,024 B

    linear_prep_kernel<<<1946 + 1568, 256, 0, stream>>>(
        x, lw, lb, f0, w2s, wsB, w1s, b1s, wsW1, guid, guid4);
    bicubic_kernel<<<(BATCH * HW + 255) / 256, 256, 0, stream>>>(f0, hr4A);

    dim3 jgrid(14, 14, BATCH), jblock(16, 16);
    const float4* hins[4]  = { hr4A, hr4B, hr4A, hr4B };
    float4*       fouts[4] = { hr4B, hr4A, hr4B, nullptr };
    for (int s = 0; s < 4; s++) {
        jbu_kernel<<<jgrid, jblock, 0, stream>>>(
            guid4, wsW1, wsB, b2s + s * 32,
            hins[s], fouts[s], (s == 3) ? (float*)d_out : nullptr,
            temps, sigmas, s);
    }
}